// Round 3
// baseline (268.445 us; speedup 1.0000x reference)
//
#include <hip/hip_runtime.h>

// Histogram2D: x (16, 131072, 2) f32 in [0,1) -> counts (16, 100, 100) f32, normalized.
// Round 3: (a) LDS atomics via unsafeAtomicAdd -> hardware ds_add_f32 (plain atomicAdd
// on f32 LDS compiles to a CAS loop without -munsafe-fp-atomics -> ~130cy round-trip
// per site = the round-1/2 latency wall); (b) fully branchless unconditional 11-site
// adds (w = fmax(w,0) at clamped addresses; +0.0f adds are exact no-ops); (c) mul-based
// binning; (d) single fused reduce+normalize kernel (2 dispatches, no memset).

#define BINS     100
#define NBINS2   (BINS * BINS)     // 10000
#define NPOINTS  131072
#define NBATCH   16
#define PPB      32                // partial blocks per batch
#define CHUNK    (NPOINTS / PPB)   // 4096 points per block
#define THREADS  1024
#define NPART    (NBATCH * PPB)    // 512

__device__ __forceinline__ void accum_point(float* lh, float x0, float x1) {
    // anchor bin: floor(x*100) clipped. (x/0.01f vs x*100 can differ only in an
    // ulp-sliver at bin edges; both anchors' windows cover the same firing set.)
    int i0 = __float2int_rd(__fmul_rn(x0, 100.0f)); i0 = min(max(i0, 0), BINS - 1);
    int i1 = __float2int_rd(__fmul_rn(x1, 100.0f)); i1 = min(max(i1, 0), BINS - 1);
    const float fi0 = (float)i0, fi1 = (float)i1;
    // centers: c = 0.01f*(n+0.5f), single rounding (matches jax f32 weak-typed DELTA)
    const float c00 = __fmul_rn(0.01f, fi0 + 0.5f);
    const float c10 = __fmul_rn(0.01f, fi1 + 0.5f);
    const float e00 = fabsf(__fsub_rn(x0, c00));
    const float e10 = fabsf(__fsub_rn(x1, c10));
    float e0m = fabsf(__fsub_rn(x0, __fmul_rn(0.01f, fi0 - 0.5f)));
    float e0p = fabsf(__fsub_rn(x0, __fmul_rn(0.01f, fi0 + 1.5f)));
    float e1m = fabsf(__fsub_rn(x1, __fmul_rn(0.01f, fi1 - 0.5f)));
    float e1p = fabsf(__fsub_rn(x1, __fmul_rn(0.01f, fi1 + 1.5f)));
    e0m = (i0 > 0)        ? e0m : 1e9f;   // OOB neighbor -> w <= 0 -> adds +0
    e0p = (i0 < BINS - 1) ? e0p : 1e9f;
    e1m = (i1 > 0)        ? e1m : 1e9f;
    e1p = (i1 < BINS - 1) ? e1p : 1e9f;
    // the only +/-2 offset that can fire is on the side the point leans toward,
    // and only paired with the other coordinate's own bin.
    const bool up0 = (x0 > c00), up1 = (x1 > c10);
    const int   f0  = up0 ? i0 + 2 : i0 - 2;
    const int   f1  = up1 ? i1 + 2 : i1 - 2;
    const float ff0 = up0 ? fi0 + 2.0f : fi0 - 2.0f;
    const float ff1 = up1 ? fi1 + 2.0f : fi1 - 2.0f;
    float e0f = fabsf(__fsub_rn(x0, __fmul_rn(0.01f, ff0 + 0.5f)));
    float e1f = fabsf(__fsub_rn(x1, __fmul_rn(0.01f, ff1 + 0.5f)));
    e0f = ((unsigned)f0 < (unsigned)BINS) ? e0f : 1e9f;
    e1f = ((unsigned)f1 < (unsigned)BINS) ? e1f : 1e9f;

    const int rm = max(i0 - 1, 0) * BINS;
    const int r0 = i0 * BINS;
    const int rp = min(i0 + 1, BINS - 1) * BINS;
    const int rf = min(max(f0, 0), BINS - 1) * BINS;
    const int cm = max(i1 - 1, 0);
    const int cc = i1;
    const int cp = min(i1 + 1, BINS - 1);
    const int cf = min(max(f1, 0), BINS - 1);

    // w = relu(0.01 - 0.5*(d0+d1)); fma(-0.5,t,0.01) == fsub(0.01, fmul(0.5,t))
    // exactly (0.5*t is exact, both round once). Unconditional hardware ds_add_f32.
#define SITE(EA, EB, RA, CB) do {                                              \
        const float w_ = fmaxf(fmaf(-0.5f, __fadd_rn(EA, EB), 0.01f), 0.0f);   \
        unsafeAtomicAdd(&lh[(RA) + (CB)], w_);                                 \
    } while (0)
    SITE(e0m, e1m, rm, cm); SITE(e0m, e10, rm, cc); SITE(e0m, e1p, rm, cp);
    SITE(e00, e1m, r0, cm); SITE(e00, e10, r0, cc); SITE(e00, e1p, r0, cp);
    SITE(e0p, e1m, rp, cm); SITE(e0p, e10, rp, cc); SITE(e0p, e1p, rp, cp);
    SITE(e0f, e10, rf, cc);
    SITE(e00, e1f, r0, cf);
#undef SITE
}

// ---- main path: per-block LDS hist -> plain-store partials into ws ----
__global__ __launch_bounds__(THREADS) void hist_part_kernel(
    const float* __restrict__ x, float* __restrict__ part)
{
    __shared__ __align__(16) float lh[NBINS2];
    float4* lh4 = (float4*)lh;
    for (int i = threadIdx.x; i < NBINS2 / 4; i += THREADS)
        lh4[i] = make_float4(0.f, 0.f, 0.f, 0.f);
    __syncthreads();

    const int b  = blockIdx.x / PPB;
    const int pb = blockIdx.x % PPB;
    const float4* __restrict__ xp = reinterpret_cast<const float4*>(
        x + (size_t)b * (NPOINTS * 2) + (size_t)pb * (CHUNK * 2));

    #pragma unroll
    for (int k = 0; k < (CHUNK / 2) / THREADS; ++k) {
        const float4 p = xp[threadIdx.x + k * THREADS];
        accum_point(lh, p.x, p.y);
        accum_point(lh, p.z, p.w);
    }
    __syncthreads();

    float4* __restrict__ po4 = (float4*)(part + (size_t)blockIdx.x * NBINS2);
    for (int i = threadIdx.x; i < NBINS2 / 4; i += THREADS) po4[i] = lh4[i];
}

// 16 blocks: sum 32 partials per bin, compute batch total, normalize, store.
__global__ __launch_bounds__(1024) void reduce_norm_kernel(
    const float* __restrict__ part, float* __restrict__ out)
{
    const int b = blockIdx.x;
    const float* __restrict__ pb = part + (size_t)b * PPB * NBINS2;
    float s[10];
    float tsum = 0.0f;
    #pragma unroll
    for (int k = 0; k < 10; ++k) {
        const int bin = threadIdx.x + k * 1024;
        float a0 = 0.f, a1 = 0.f, a2 = 0.f, a3 = 0.f;
        if (bin < NBINS2) {
            #pragma unroll
            for (int p = 0; p < PPB; p += 4) {
                a0 += pb[(size_t)p       * NBINS2 + bin];
                a1 += pb[(size_t)(p + 1) * NBINS2 + bin];
                a2 += pb[(size_t)(p + 2) * NBINS2 + bin];
                a3 += pb[(size_t)(p + 3) * NBINS2 + bin];
            }
        }
        s[k] = (a0 + a1) + (a2 + a3);
        tsum += s[k];
    }
    #pragma unroll
    for (int off = 32; off > 0; off >>= 1) tsum += __shfl_down(tsum, off, 64);
    __shared__ float wsum[16];
    __shared__ float sden;
    if ((threadIdx.x & 63) == 0) wsum[threadIdx.x >> 6] = tsum;
    __syncthreads();
    if (threadIdx.x == 0) {
        float t = 0.f;
        #pragma unroll
        for (int i = 0; i < 16; ++i) t += wsum[i];
        sden = __fadd_rn(t, 1e-5f);
    }
    __syncthreads();
    const float den = sden;
    #pragma unroll
    for (int k = 0; k < 10; ++k) {
        const int bin = threadIdx.x + k * 1024;
        if (bin < NBINS2) out[(size_t)b * NBINS2 + bin] = __fdiv_rn(s[k], den);
    }
}

// ---- fallback path (ws too small): atomic flush into out + separate norm ----
__global__ __launch_bounds__(THREADS) void hist_accum_kernel(
    const float* __restrict__ x, float* __restrict__ out)
{
    __shared__ __align__(16) float lh[NBINS2];
    float4* lh4 = (float4*)lh;
    for (int i = threadIdx.x; i < NBINS2 / 4; i += THREADS)
        lh4[i] = make_float4(0.f, 0.f, 0.f, 0.f);
    __syncthreads();

    const int b  = blockIdx.x / PPB;
    const int pb = blockIdx.x % PPB;
    const float4* __restrict__ xp = reinterpret_cast<const float4*>(
        x + (size_t)b * (NPOINTS * 2) + (size_t)pb * (CHUNK * 2));

    #pragma unroll
    for (int k = 0; k < (CHUNK / 2) / THREADS; ++k) {
        const float4 p = xp[threadIdx.x + k * THREADS];
        accum_point(lh, p.x, p.y);
        accum_point(lh, p.z, p.w);
    }
    __syncthreads();

    float* __restrict__ ob = out + (size_t)b * NBINS2;
    for (int i = threadIdx.x; i < NBINS2; i += THREADS) {
        const float v = lh[i];
        if (v != 0.0f) unsafeAtomicAdd(&ob[i], v);
    }
}

__global__ __launch_bounds__(1024) void norm_kernel(float* __restrict__ out)
{
    const int b = blockIdx.x;
    float* __restrict__ h = out + (size_t)b * NBINS2;
    float local = 0.0f;
    for (int i = threadIdx.x; i < NBINS2; i += 1024) local += h[i];
    #pragma unroll
    for (int off = 32; off > 0; off >>= 1) local += __shfl_down(local, off, 64);

    __shared__ float wsum[16];
    __shared__ float sden;
    if ((threadIdx.x & 63) == 0) wsum[threadIdx.x >> 6] = local;
    __syncthreads();
    if (threadIdx.x == 0) {
        float t = 0.f;
        #pragma unroll
        for (int i = 0; i < 16; ++i) t += wsum[i];
        sden = __fadd_rn(t, 1e-5f);
    }
    __syncthreads();
    const float den = sden;
    for (int i = threadIdx.x; i < NBINS2; i += 1024) h[i] = __fdiv_rn(h[i], den);
}

extern "C" void kernel_launch(void* const* d_in, const int* in_sizes, int n_in,
                              void* d_out, int out_size, void* d_ws, size_t ws_size,
                              hipStream_t stream) {
    (void)in_sizes; (void)n_in;
    const float* x = (const float*)d_in[0];
    float* out = (float*)d_out;

    const size_t need = (size_t)NPART * NBINS2 * sizeof(float);
    if (ws_size >= need) {
        float* part = (float*)d_ws;    // [512][10000] partials (fully overwritten)
        hist_part_kernel<<<NPART, THREADS, 0, stream>>>(x, part);
        reduce_norm_kernel<<<NBATCH, 1024, 0, stream>>>(part, out);
    } else {
        hipMemsetAsync(out, 0, (size_t)out_size * sizeof(float), stream);
        hist_accum_kernel<<<NPART, THREADS, 0, stream>>>(x, out);
        norm_kernel<<<NBATCH, 1024, 0, stream>>>(out);
    }
}

// Round 4
// 223.287 us; speedup vs baseline: 1.2022x; 1.2022x over previous
//
#include <hip/hip_runtime.h>

// Histogram2D: x (16, 131072, 2) f32 in [0,1) -> counts (16, 100, 100) f32, normalized.
// Round 4: the r1-r3 wall is LDS f32 atomic throughput (~3.2 cyc per ACTIVE LANE,
// serialized per CU; cost tracks lanes not instrs/banks). Switch the LDS histogram to
// FIXED-POINT u32 (ds_add_u32, quantum 2^-25) - integer RMW may be banked-parallel
// unlike the serial FP path - and mask every site with if(w>0) (only ~7.5 of 11 fire).
// Partials reduce exactly in u64, normalize in double. Errors ~1e-9 normalized.

#define BINS     100
#define NBINS2   (BINS * BINS)     // 10000
#define NPOINTS  131072
#define NBATCH   16
#define PPB      32                // partial blocks per batch
#define CHUNK    (NPOINTS / PPB)   // 4096 points per block
#define THREADS  1024
#define NPART    (NBATCH * PPB)    // 512
#define QSCALE   33554432.0f       // 2^25 fixed-point scale
#define QINV     (1.0 / 33554432.0)

__device__ __forceinline__ void accum_point_q(unsigned* lh, float x0, float x1) {
    // anchor bin: floor(x*100) clipped (same anchor as r3, verified passing)
    int i0 = __float2int_rd(__fmul_rn(x0, 100.0f)); i0 = min(max(i0, 0), BINS - 1);
    int i1 = __float2int_rd(__fmul_rn(x1, 100.0f)); i1 = min(max(i1, 0), BINS - 1);
    const float fi0 = (float)i0, fi1 = (float)i1;
    const float c00 = __fmul_rn(0.01f, fi0 + 0.5f);
    const float c10 = __fmul_rn(0.01f, fi1 + 0.5f);
    const float e00 = fabsf(__fsub_rn(x0, c00));
    const float e10 = fabsf(__fsub_rn(x1, c10));
    float e0m = fabsf(__fsub_rn(x0, __fmul_rn(0.01f, fi0 - 0.5f)));
    float e0p = fabsf(__fsub_rn(x0, __fmul_rn(0.01f, fi0 + 1.5f)));
    float e1m = fabsf(__fsub_rn(x1, __fmul_rn(0.01f, fi1 - 0.5f)));
    float e1p = fabsf(__fsub_rn(x1, __fmul_rn(0.01f, fi1 + 1.5f)));
    e0m = (i0 > 0)        ? e0m : 1e9f;   // OOB neighbor -> w < 0 -> masked
    e0p = (i0 < BINS - 1) ? e0p : 1e9f;
    e1m = (i1 > 0)        ? e1m : 1e9f;
    e1p = (i1 < BINS - 1) ? e1p : 1e9f;
    // only the leaned-toward +/-2 offset can fire, paired with the other coord's own bin
    const bool up0 = (x0 > c00), up1 = (x1 > c10);
    const int   f0  = up0 ? i0 + 2 : i0 - 2;
    const int   f1  = up1 ? i1 + 2 : i1 - 2;
    const float ff0 = up0 ? fi0 + 2.0f : fi0 - 2.0f;
    const float ff1 = up1 ? fi1 + 2.0f : fi1 - 2.0f;
    float e0f = fabsf(__fsub_rn(x0, __fmul_rn(0.01f, ff0 + 0.5f)));
    float e1f = fabsf(__fsub_rn(x1, __fmul_rn(0.01f, ff1 + 0.5f)));
    e0f = ((unsigned)f0 < (unsigned)BINS) ? e0f : 1e9f;
    e1f = ((unsigned)f1 < (unsigned)BINS) ? e1f : 1e9f;

    const int rm = max(i0 - 1, 0) * BINS;
    const int r0 = i0 * BINS;
    const int rp = min(i0 + 1, BINS - 1) * BINS;
    const int rf = min(max(f0, 0), BINS - 1) * BINS;
    const int cm = max(i1 - 1, 0);
    const int cc = i1;
    const int cp = min(i1 + 1, BINS - 1);
    const int cf = min(max(f1, 0), BINS - 1);

    // w = relu(0.01 - 0.5*(d0+d1)); fired sites only -> ds_add_u32 of round(w*2^25)
#define SITEQ(EA, EB, ADDR) do {                                               \
        const float w_ = fmaf(-0.5f, __fadd_rn(EA, EB), 0.01f);                \
        if (w_ > 0.0f)                                                         \
            atomicAdd(&lh[ADDR], (unsigned)fmaf(w_, QSCALE, 0.5f));            \
    } while (0)
    SITEQ(e0m, e1m, rm + cm); SITEQ(e0m, e10, rm + cc); SITEQ(e0m, e1p, rm + cp);
    SITEQ(e00, e1m, r0 + cm); SITEQ(e00, e10, r0 + cc); SITEQ(e00, e1p, r0 + cp);
    SITEQ(e0p, e1m, rp + cm); SITEQ(e0p, e10, rp + cc); SITEQ(e0p, e1p, rp + cp);
    SITEQ(e0f, e10, rf + cc);
    SITEQ(e00, e1f, r0 + cf);
#undef SITEQ
}

// ---- main path: per-block u32 LDS hist -> plain-store partials into ws ----
__global__ __launch_bounds__(THREADS) void hist_part_kernel(
    const float* __restrict__ x, unsigned* __restrict__ part)
{
    __shared__ __align__(16) unsigned lh[NBINS2];
    uint4* lh4 = (uint4*)lh;
    for (int i = threadIdx.x; i < NBINS2 / 4; i += THREADS)
        lh4[i] = make_uint4(0u, 0u, 0u, 0u);
    __syncthreads();

    const int b  = blockIdx.x / PPB;
    const int pb = blockIdx.x % PPB;
    const float4* __restrict__ xp = reinterpret_cast<const float4*>(
        x + (size_t)b * (NPOINTS * 2) + (size_t)pb * (CHUNK * 2));

    #pragma unroll
    for (int k = 0; k < (CHUNK / 2) / THREADS; ++k) {
        const float4 p = xp[threadIdx.x + k * THREADS];
        accum_point_q(lh, p.x, p.y);
        accum_point_q(lh, p.z, p.w);
    }
    __syncthreads();

    uint4* __restrict__ po4 = (uint4*)(part + (size_t)blockIdx.x * NBINS2);
    for (int i = threadIdx.x; i < NBINS2 / 4; i += THREADS) po4[i] = lh4[i];
}

// 16 blocks: sum 32 u32 partials per bin exactly (u64), normalize in double.
__global__ __launch_bounds__(1024) void reduce_norm_kernel(
    const unsigned* __restrict__ part, float* __restrict__ out)
{
    const int b = blockIdx.x;
    const unsigned* __restrict__ pb = part + (size_t)b * PPB * NBINS2;
    unsigned long long s[10];
    unsigned long long t = 0ull;
    #pragma unroll
    for (int k = 0; k < 10; ++k) {
        const int bin = threadIdx.x + k * 1024;
        unsigned long long a = 0ull;
        if (bin < NBINS2) {
            #pragma unroll
            for (int p = 0; p < PPB; ++p) a += pb[(size_t)p * NBINS2 + bin];
        }
        s[k] = a; t += a;
    }
    double td = (double)t;
    #pragma unroll
    for (int off = 32; off > 0; off >>= 1) td += __shfl_down(td, off, 64);
    __shared__ double wsum[16];
    __shared__ double sfac;
    if ((threadIdx.x & 63) == 0) wsum[threadIdx.x >> 6] = td;
    __syncthreads();
    if (threadIdx.x == 0) {
        double tt = 0.0;
        #pragma unroll
        for (int i = 0; i < 16; ++i) tt += wsum[i];
        sfac = QINV / (tt * QINV + 1e-5);   // counts*QINV / (total*QINV + 1e-5)
    }
    __syncthreads();
    const double fac = sfac;
    #pragma unroll
    for (int k = 0; k < 10; ++k) {
        const int bin = threadIdx.x + k * 1024;
        if (bin < NBINS2)
            out[(size_t)b * NBINS2 + bin] = (float)((double)s[k] * fac);
    }
}

// ---- fallback path (ws too small): float LDS hist + global atomic flush ----
__device__ __forceinline__ void accum_point_f(float* lh, float x0, float x1) {
    int i0 = __float2int_rd(__fmul_rn(x0, 100.0f)); i0 = min(max(i0, 0), BINS - 1);
    int i1 = __float2int_rd(__fmul_rn(x1, 100.0f)); i1 = min(max(i1, 0), BINS - 1);
    const float fi0 = (float)i0, fi1 = (float)i1;
    const float c00 = __fmul_rn(0.01f, fi0 + 0.5f);
    const float c10 = __fmul_rn(0.01f, fi1 + 0.5f);
    const float e00 = fabsf(__fsub_rn(x0, c00));
    const float e10 = fabsf(__fsub_rn(x1, c10));
    float e0m = fabsf(__fsub_rn(x0, __fmul_rn(0.01f, fi0 - 0.5f)));
    float e0p = fabsf(__fsub_rn(x0, __fmul_rn(0.01f, fi0 + 1.5f)));
    float e1m = fabsf(__fsub_rn(x1, __fmul_rn(0.01f, fi1 - 0.5f)));
    float e1p = fabsf(__fsub_rn(x1, __fmul_rn(0.01f, fi1 + 1.5f)));
    e0m = (i0 > 0)        ? e0m : 1e9f;
    e0p = (i0 < BINS - 1) ? e0p : 1e9f;
    e1m = (i1 > 0)        ? e1m : 1e9f;
    e1p = (i1 < BINS - 1) ? e1p : 1e9f;
    const bool up0 = (x0 > c00), up1 = (x1 > c10);
    const int   f0  = up0 ? i0 + 2 : i0 - 2;
    const int   f1  = up1 ? i1 + 2 : i1 - 2;
    const float ff0 = up0 ? fi0 + 2.0f : fi0 - 2.0f;
    const float ff1 = up1 ? fi1 + 2.0f : fi1 - 2.0f;
    float e0f = fabsf(__fsub_rn(x0, __fmul_rn(0.01f, ff0 + 0.5f)));
    float e1f = fabsf(__fsub_rn(x1, __fmul_rn(0.01f, ff1 + 0.5f)));
    e0f = ((unsigned)f0 < (unsigned)BINS) ? e0f : 1e9f;
    e1f = ((unsigned)f1 < (unsigned)BINS) ? e1f : 1e9f;
    const int rm = max(i0 - 1, 0) * BINS;
    const int r0 = i0 * BINS;
    const int rp = min(i0 + 1, BINS - 1) * BINS;
    const int rf = min(max(f0, 0), BINS - 1) * BINS;
    const int cm = max(i1 - 1, 0);
    const int cc = i1;
    const int cp = min(i1 + 1, BINS - 1);
    const int cf = min(max(f1, 0), BINS - 1);
#define SITEF(EA, EB, ADDR) do {                                               \
        const float w_ = fmaf(-0.5f, __fadd_rn(EA, EB), 0.01f);                \
        if (w_ > 0.0f) unsafeAtomicAdd(&lh[ADDR], w_);                         \
    } while (0)
    SITEF(e0m, e1m, rm + cm); SITEF(e0m, e10, rm + cc); SITEF(e0m, e1p, rm + cp);
    SITEF(e00, e1m, r0 + cm); SITEF(e00, e10, r0 + cc); SITEF(e00, e1p, r0 + cp);
    SITEF(e0p, e1m, rp + cm); SITEF(e0p, e10, rp + cc); SITEF(e0p, e1p, rp + cp);
    SITEF(e0f, e10, rf + cc);
    SITEF(e00, e1f, r0 + cf);
#undef SITEF
}

__global__ __launch_bounds__(THREADS) void hist_accum_kernel(
    const float* __restrict__ x, float* __restrict__ out)
{
    __shared__ __align__(16) float lh[NBINS2];
    float4* lh4 = (float4*)lh;
    for (int i = threadIdx.x; i < NBINS2 / 4; i += THREADS)
        lh4[i] = make_float4(0.f, 0.f, 0.f, 0.f);
    __syncthreads();
    const int b  = blockIdx.x / PPB;
    const int pb = blockIdx.x % PPB;
    const float4* __restrict__ xp = reinterpret_cast<const float4*>(
        x + (size_t)b * (NPOINTS * 2) + (size_t)pb * (CHUNK * 2));
    #pragma unroll
    for (int k = 0; k < (CHUNK / 2) / THREADS; ++k) {
        const float4 p = xp[threadIdx.x + k * THREADS];
        accum_point_f(lh, p.x, p.y);
        accum_point_f(lh, p.z, p.w);
    }
    __syncthreads();
    float* __restrict__ ob = out + (size_t)b * NBINS2;
    for (int i = threadIdx.x; i < NBINS2; i += THREADS) {
        const float v = lh[i];
        if (v != 0.0f) unsafeAtomicAdd(&ob[i], v);
    }
}

__global__ __launch_bounds__(1024) void norm_kernel(float* __restrict__ out)
{
    const int b = blockIdx.x;
    float* __restrict__ h = out + (size_t)b * NBINS2;
    float local = 0.0f;
    for (int i = threadIdx.x; i < NBINS2; i += 1024) local += h[i];
    #pragma unroll
    for (int off = 32; off > 0; off >>= 1) local += __shfl_down(local, off, 64);
    __shared__ float wsum[16];
    __shared__ float sden;
    if ((threadIdx.x & 63) == 0) wsum[threadIdx.x >> 6] = local;
    __syncthreads();
    if (threadIdx.x == 0) {
        float tt = 0.f;
        #pragma unroll
        for (int i = 0; i < 16; ++i) tt += wsum[i];
        sden = __fadd_rn(tt, 1e-5f);
    }
    __syncthreads();
    const float den = sden;
    for (int i = threadIdx.x; i < NBINS2; i += 1024) h[i] = __fdiv_rn(h[i], den);
}

extern "C" void kernel_launch(void* const* d_in, const int* in_sizes, int n_in,
                              void* d_out, int out_size, void* d_ws, size_t ws_size,
                              hipStream_t stream) {
    (void)in_sizes; (void)n_in;
    const float* x = (const float*)d_in[0];
    float* out = (float*)d_out;

    const size_t need = (size_t)NPART * NBINS2 * sizeof(unsigned);
    if (ws_size >= need) {
        unsigned* part = (unsigned*)d_ws;   // [512][10000] u32 partials (overwritten)
        hist_part_kernel<<<NPART, THREADS, 0, stream>>>(x, part);
        reduce_norm_kernel<<<NBATCH, 1024, 0, stream>>>(part, out);
    } else {
        hipMemsetAsync(out, 0, (size_t)out_size * sizeof(float), stream);
        hist_accum_kernel<<<NPART, THREADS, 0, stream>>>(x, out);
        norm_kernel<<<NBATCH, 1024, 0, stream>>>(out);
    }
}

// Round 5
// 158.207 us; speedup vs baseline: 1.6968x; 1.4114x over previous
//
#include <hip/hip_runtime.h>

// Histogram2D: x (16, 131072, 2) f32 in [0,1) -> counts (16, 100, 100) f32, normalized.
// Round 5: r4's reduce_norm ran 16 blocks (6% of GPU) -> 155us at 0.3% occupancy.
// (a) reduce now 160 blocks, 1000 bins each, 32-partial sum; (b) per-batch totals are
// computed exactly (u64) inside hist_part's flush (wave-reduce + 16 u64 atomics/block);
// (c) hist sites: center+4 edges fire always -> unconditional fmax-adds, only corners
// (~50%) and far sites (~25%) keep the w>0 mask. LDS hist stays fixed-point u32
// (quantum 2^-25, hard per-block per-bin max 41*2^25 = 1.37e9 < 2^32).

#define BINS     100
#define NBINS2   (BINS * BINS)     // 10000
#define NPOINTS  131072
#define NBATCH   16
#define PPB      32                // partial blocks per batch
#define CHUNK    (NPOINTS / PPB)   // 4096 points per block
#define THREADS  1024
#define NPART    (NBATCH * PPB)    // 512
#define QSCALE   33554432.0f       // 2^25 fixed-point scale
#define QINV     (1.0 / 33554432.0)

__device__ __forceinline__ void accum_point_q(unsigned* lh, float x0, float x1) {
    // anchor bin: floor(x*100) clipped
    int i0 = __float2int_rd(__fmul_rn(x0, 100.0f)); i0 = min(max(i0, 0), BINS - 1);
    int i1 = __float2int_rd(__fmul_rn(x1, 100.0f)); i1 = min(max(i1, 0), BINS - 1);
    const float fi0 = (float)i0, fi1 = (float)i1;
    const float c00 = __fmul_rn(0.01f, fi0 + 0.5f);
    const float c10 = __fmul_rn(0.01f, fi1 + 0.5f);
    const float e00 = fabsf(__fsub_rn(x0, c00));
    const float e10 = fabsf(__fsub_rn(x1, c10));
    float e0m = fabsf(__fsub_rn(x0, __fmul_rn(0.01f, fi0 - 0.5f)));
    float e0p = fabsf(__fsub_rn(x0, __fmul_rn(0.01f, fi0 + 1.5f)));
    float e1m = fabsf(__fsub_rn(x1, __fmul_rn(0.01f, fi1 - 0.5f)));
    float e1p = fabsf(__fsub_rn(x1, __fmul_rn(0.01f, fi1 + 1.5f)));
    e0m = (i0 > 0)        ? e0m : 1e9f;   // OOB neighbor -> w <= 0 -> adds 0 / masked
    e0p = (i0 < BINS - 1) ? e0p : 1e9f;
    e1m = (i1 > 0)        ? e1m : 1e9f;
    e1p = (i1 < BINS - 1) ? e1p : 1e9f;
    // only the leaned-toward +/-2 offset can fire, paired with the other coord's own bin
    const bool up0 = (x0 > c00), up1 = (x1 > c10);
    const int   f0  = up0 ? i0 + 2 : i0 - 2;
    const int   f1  = up1 ? i1 + 2 : i1 - 2;
    const float ff0 = up0 ? fi0 + 2.0f : fi0 - 2.0f;
    const float ff1 = up1 ? fi1 + 2.0f : fi1 - 2.0f;
    float e0f = fabsf(__fsub_rn(x0, __fmul_rn(0.01f, ff0 + 0.5f)));
    float e1f = fabsf(__fsub_rn(x1, __fmul_rn(0.01f, ff1 + 0.5f)));
    e0f = ((unsigned)f0 < (unsigned)BINS) ? e0f : 1e9f;
    e1f = ((unsigned)f1 < (unsigned)BINS) ? e1f : 1e9f;

    const int rm = max(i0 - 1, 0) * BINS;
    const int r0 = i0 * BINS;
    const int rp = min(i0 + 1, BINS - 1) * BINS;
    const int rf = min(max(f0, 0), BINS - 1) * BINS;
    const int cm = max(i1 - 1, 0);
    const int cc = i1;
    const int cp = min(i1 + 1, BINS - 1);
    const int cf = min(max(f1, 0), BINS - 1);

    // unconditional sites (center + 4 edges: mathematically always fire when in-bounds;
    // fmax clamps the OOB 1e9 path to a +0 add)
#define SITEU(EA, EB, ADDR) do {                                               \
        const float w_ = fmaxf(fmaf(-0.5f, __fadd_rn(EA, EB), 0.01f), 0.0f);   \
        atomicAdd(&lh[ADDR], (unsigned)fmaf(w_, QSCALE, 0.5f));                \
    } while (0)
    // masked sites (corners ~50%, far ~25%)
#define SITEQ(EA, EB, ADDR) do {                                               \
        const float w_ = fmaf(-0.5f, __fadd_rn(EA, EB), 0.01f);                \
        if (w_ > 0.0f)                                                         \
            atomicAdd(&lh[ADDR], (unsigned)fmaf(w_, QSCALE, 0.5f));            \
    } while (0)
    SITEQ(e0m, e1m, rm + cm); SITEU(e0m, e10, rm + cc); SITEQ(e0m, e1p, rm + cp);
    SITEU(e00, e1m, r0 + cm); SITEU(e00, e10, r0 + cc); SITEU(e00, e1p, r0 + cp);
    SITEQ(e0p, e1m, rp + cm); SITEU(e0p, e10, rp + cc); SITEQ(e0p, e1p, rp + cp);
    SITEQ(e0f, e10, rf + cc);
    SITEQ(e00, e1f, r0 + cf);
#undef SITEU
#undef SITEQ
}

// ---- main path: per-block u32 LDS hist -> partials + exact u64 batch totals ----
__global__ __launch_bounds__(THREADS) void hist_part_kernel(
    const float* __restrict__ x, unsigned* __restrict__ part,
    unsigned long long* __restrict__ totals)
{
    __shared__ __align__(16) unsigned lh[NBINS2];
    uint4* lh4 = (uint4*)lh;
    for (int i = threadIdx.x; i < NBINS2 / 4; i += THREADS)
        lh4[i] = make_uint4(0u, 0u, 0u, 0u);
    __syncthreads();

    const int b  = blockIdx.x / PPB;
    const int pb = blockIdx.x % PPB;
    const float4* __restrict__ xp = reinterpret_cast<const float4*>(
        x + (size_t)b * (NPOINTS * 2) + (size_t)pb * (CHUNK * 2));

    #pragma unroll
    for (int k = 0; k < (CHUNK / 2) / THREADS; ++k) {
        const float4 p = xp[threadIdx.x + k * THREADS];
        accum_point_q(lh, p.x, p.y);
        accum_point_q(lh, p.z, p.w);
    }
    __syncthreads();

    uint4* __restrict__ po4 = (uint4*)(part + (size_t)blockIdx.x * NBINS2);
    unsigned long long ts = 0ull;
    for (int i = threadIdx.x; i < NBINS2 / 4; i += THREADS) {
        const uint4 v = lh4[i];
        po4[i] = v;
        ts += (unsigned long long)v.x + v.y + v.z + v.w;
    }
    #pragma unroll
    for (int off = 32; off > 0; off >>= 1) ts += __shfl_down(ts, off, 64);
    if ((threadIdx.x & 63) == 0) atomicAdd(&totals[b], ts);
}

// 160 blocks: (b = blk&15, q = blk>>4); sum 32 partials for 1000 bins, normalize.
__global__ __launch_bounds__(1024) void reduce_norm_kernel(
    const unsigned* __restrict__ part, const unsigned long long* __restrict__ totals,
    float* __restrict__ out)
{
    const int b = blockIdx.x & 15;
    const int q = blockIdx.x >> 4;
    const int t = threadIdx.x;
    if (t < 1000) {
        const int bin = q * 1000 + t;
        const unsigned* __restrict__ pp = part + (size_t)b * PPB * NBINS2 + bin;
        unsigned long long s0 = 0ull, s1 = 0ull;
        #pragma unroll
        for (int p = 0; p < PPB; p += 2) {
            s0 += pp[(size_t)p       * NBINS2];
            s1 += pp[(size_t)(p + 1) * NBINS2];
        }
        const double T   = (double)totals[b];
        const double fac = QINV / (T * QINV + 1e-5);
        out[(size_t)b * NBINS2 + bin] = (float)((double)(s0 + s1) * fac);
    }
}

// ---- fallback path (ws too small): float LDS hist + global atomic flush ----
__device__ __forceinline__ void accum_point_f(float* lh, float x0, float x1) {
    int i0 = __float2int_rd(__fmul_rn(x0, 100.0f)); i0 = min(max(i0, 0), BINS - 1);
    int i1 = __float2int_rd(__fmul_rn(x1, 100.0f)); i1 = min(max(i1, 0), BINS - 1);
    const float fi0 = (float)i0, fi1 = (float)i1;
    const float c00 = __fmul_rn(0.01f, fi0 + 0.5f);
    const float c10 = __fmul_rn(0.01f, fi1 + 0.5f);
    const float e00 = fabsf(__fsub_rn(x0, c00));
    const float e10 = fabsf(__fsub_rn(x1, c10));
    float e0m = fabsf(__fsub_rn(x0, __fmul_rn(0.01f, fi0 - 0.5f)));
    float e0p = fabsf(__fsub_rn(x0, __fmul_rn(0.01f, fi0 + 1.5f)));
    float e1m = fabsf(__fsub_rn(x1, __fmul_rn(0.01f, fi1 - 0.5f)));
    float e1p = fabsf(__fsub_rn(x1, __fmul_rn(0.01f, fi1 + 1.5f)));
    e0m = (i0 > 0)        ? e0m : 1e9f;
    e0p = (i0 < BINS - 1) ? e0p : 1e9f;
    e1m = (i1 > 0)        ? e1m : 1e9f;
    e1p = (i1 < BINS - 1) ? e1p : 1e9f;
    const bool up0 = (x0 > c00), up1 = (x1 > c10);
    const int   f0  = up0 ? i0 + 2 : i0 - 2;
    const int   f1  = up1 ? i1 + 2 : i1 - 2;
    const float ff0 = up0 ? fi0 + 2.0f : fi0 - 2.0f;
    const float ff1 = up1 ? fi1 + 2.0f : fi1 - 2.0f;
    float e0f = fabsf(__fsub_rn(x0, __fmul_rn(0.01f, ff0 + 0.5f)));
    float e1f = fabsf(__fsub_rn(x1, __fmul_rn(0.01f, ff1 + 0.5f)));
    e0f = ((unsigned)f0 < (unsigned)BINS) ? e0f : 1e9f;
    e1f = ((unsigned)f1 < (unsigned)BINS) ? e1f : 1e9f;
    const int rm = max(i0 - 1, 0) * BINS;
    const int r0 = i0 * BINS;
    const int rp = min(i0 + 1, BINS - 1) * BINS;
    const int rf = min(max(f0, 0), BINS - 1) * BINS;
    const int cm = max(i1 - 1, 0);
    const int cc = i1;
    const int cp = min(i1 + 1, BINS - 1);
    const int cf = min(max(f1, 0), BINS - 1);
#define SITEF(EA, EB, ADDR) do {                                               \
        const float w_ = fmaf(-0.5f, __fadd_rn(EA, EB), 0.01f);                \
        if (w_ > 0.0f) unsafeAtomicAdd(&lh[ADDR], w_);                         \
    } while (0)
    SITEF(e0m, e1m, rm + cm); SITEF(e0m, e10, rm + cc); SITEF(e0m, e1p, rm + cp);
    SITEF(e00, e1m, r0 + cm); SITEF(e00, e10, r0 + cc); SITEF(e00, e1p, r0 + cp);
    SITEF(e0p, e1m, rp + cm); SITEF(e0p, e10, rp + cc); SITEF(e0p, e1p, rp + cp);
    SITEF(e0f, e10, rf + cc);
    SITEF(e00, e1f, r0 + cf);
#undef SITEF
}

__global__ __launch_bounds__(THREADS) void hist_accum_kernel(
    const float* __restrict__ x, float* __restrict__ out)
{
    __shared__ __align__(16) float lh[NBINS2];
    float4* lh4 = (float4*)lh;
    for (int i = threadIdx.x; i < NBINS2 / 4; i += THREADS)
        lh4[i] = make_float4(0.f, 0.f, 0.f, 0.f);
    __syncthreads();
    const int b  = blockIdx.x / PPB;
    const int pb = blockIdx.x % PPB;
    const float4* __restrict__ xp = reinterpret_cast<const float4*>(
        x + (size_t)b * (NPOINTS * 2) + (size_t)pb * (CHUNK * 2));
    #pragma unroll
    for (int k = 0; k < (CHUNK / 2) / THREADS; ++k) {
        const float4 p = xp[threadIdx.x + k * THREADS];
        accum_point_f(lh, p.x, p.y);
        accum_point_f(lh, p.z, p.w);
    }
    __syncthreads();
    float* __restrict__ ob = out + (size_t)b * NBINS2;
    for (int i = threadIdx.x; i < NBINS2; i += THREADS) {
        const float v = lh[i];
        if (v != 0.0f) unsafeAtomicAdd(&ob[i], v);
    }
}

__global__ __launch_bounds__(1024) void norm_kernel(float* __restrict__ out)
{
    const int b = blockIdx.x;
    float* __restrict__ h = out + (size_t)b * NBINS2;
    float local = 0.0f;
    for (int i = threadIdx.x; i < NBINS2; i += 1024) local += h[i];
    #pragma unroll
    for (int off = 32; off > 0; off >>= 1) local += __shfl_down(local, off, 64);
    __shared__ float wsum[16];
    __shared__ float sden;
    if ((threadIdx.x & 63) == 0) wsum[threadIdx.x >> 6] = local;
    __syncthreads();
    if (threadIdx.x == 0) {
        float tt = 0.f;
        #pragma unroll
        for (int i = 0; i < 16; ++i) tt += wsum[i];
        sden = __fadd_rn(tt, 1e-5f);
    }
    __syncthreads();
    const float den = sden;
    for (int i = threadIdx.x; i < 1024 * 10; i += 1024)
        if (i < NBINS2) h[i] = __fdiv_rn(h[i], den);
}

extern "C" void kernel_launch(void* const* d_in, const int* in_sizes, int n_in,
                              void* d_out, int out_size, void* d_ws, size_t ws_size,
                              hipStream_t stream) {
    (void)in_sizes; (void)n_in;
    const float* x = (const float*)d_in[0];
    float* out = (float*)d_out;

    const size_t need = 128 + (size_t)NPART * NBINS2 * sizeof(unsigned);
    if (ws_size >= need) {
        unsigned long long* totals = (unsigned long long*)d_ws;        // [16]
        unsigned* part = (unsigned*)((char*)d_ws + 128);               // [512][10000]
        hipMemsetAsync(totals, 0, NBATCH * sizeof(unsigned long long), stream);
        hist_part_kernel<<<NPART, THREADS, 0, stream>>>(x, part, totals);
        reduce_norm_kernel<<<NBATCH * 10, 1024, 0, stream>>>(part, totals, out);
    } else {
        hipMemsetAsync(out, 0, (size_t)out_size * sizeof(float), stream);
        hist_accum_kernel<<<NPART, THREADS, 0, stream>>>(x, out);
        norm_kernel<<<NBATCH, 1024, 0, stream>>>(out);
    }
}

// Round 6
// 155.793 us; speedup vs baseline: 1.7231x; 1.0155x over previous
//
#include <hip/hip_runtime.h>

// Histogram2D: x (16, 131072, 2) f32 in [0,1) -> counts (16, 100, 100) f32, normalized.
// Round 6 model: LDS atomic engine = ~3.3 cyc per ACTIVE LANE, serial per CU, dtype-
// independent (r3 f32 3.2, r5 u32 3.3). Changes:
//  (a) center row's 3 column-sites packed into 2 ds_add_u64 (aligned 4-col window) ->
//      issued engine lanes 8 -> 7/point IF u64 RMW costs one lane (HW probe; carry into
//      hi word impossible: per-block per-bin <= 41*2^25 = 1.37e9 < 2^32).
//  (b) reduce_norm rewritten: 160 blocks x 256 thr, one uint4 (4 bins)/thread, 32
//      coalesced 16B loads, exact u64 sums, float4 store.

#define BINS     100
#define NBINS2   (BINS * BINS)     // 10000
#define NQUAD    (NBINS2 / 4)      // 2500
#define NPOINTS  131072
#define NBATCH   16
#define PPB      32                // partial blocks per batch
#define CHUNK    (NPOINTS / PPB)   // 4096 points per block
#define THREADS  1024
#define NPART    (NBATCH * PPB)    // 512
#define QSCALE   33554432.0f       // 2^25 fixed-point scale
#define QINV     (1.0 / 33554432.0)

__device__ __forceinline__ void accum_point_q(unsigned* lh, float x0, float x1) {
    // anchor bin: floor(x*100) clipped
    int i0 = __float2int_rd(__fmul_rn(x0, 100.0f)); i0 = min(max(i0, 0), BINS - 1);
    int i1 = __float2int_rd(__fmul_rn(x1, 100.0f)); i1 = min(max(i1, 0), BINS - 1);
    const float fi0 = (float)i0, fi1 = (float)i1;
    const float c00 = __fmul_rn(0.01f, fi0 + 0.5f);
    const float c10 = __fmul_rn(0.01f, fi1 + 0.5f);
    const float e00 = fabsf(__fsub_rn(x0, c00));
    const float e10 = fabsf(__fsub_rn(x1, c10));
    // row (+/-1) distances, OOB -> 1e9 (w<0 -> 0 / masked)
    float e0m = fabsf(__fsub_rn(x0, __fmul_rn(0.01f, fi0 - 0.5f)));
    float e0p = fabsf(__fsub_rn(x0, __fmul_rn(0.01f, fi0 + 1.5f)));
    e0m = (i0 > 0)        ? e0m : 1e9f;
    e0p = (i0 < BINS - 1) ? e0p : 1e9f;
    // col (+/-1) distances for the corner sites
    float e1m = fabsf(__fsub_rn(x1, __fmul_rn(0.01f, fi1 - 0.5f)));
    float e1p = fabsf(__fsub_rn(x1, __fmul_rn(0.01f, fi1 + 1.5f)));
    e1m = (i1 > 0)        ? e1m : 1e9f;
    e1p = (i1 < BINS - 1) ? e1p : 1e9f;
    // only the leaned-toward +/-2 offset can fire, paired with the other coord's own bin
    const bool up0 = (x0 > c00), up1 = (x1 > c10);
    const int   f0  = up0 ? i0 + 2 : i0 - 2;
    const int   f1  = up1 ? i1 + 2 : i1 - 2;
    const float ff0 = up0 ? fi0 + 2.0f : fi0 - 2.0f;
    const float ff1 = up1 ? fi1 + 2.0f : fi1 - 2.0f;
    float e0f = fabsf(__fsub_rn(x0, __fmul_rn(0.01f, ff0 + 0.5f)));
    float e1f = fabsf(__fsub_rn(x1, __fmul_rn(0.01f, ff1 + 0.5f)));
    e0f = ((unsigned)f0 < (unsigned)BINS) ? e0f : 1e9f;
    e1f = ((unsigned)f1 < (unsigned)BINS) ? e1f : 1e9f;

    const int rm = max(i0 - 1, 0) * BINS;
    const int r0 = i0 * BINS;
    const int rp = min(i0 + 1, BINS - 1) * BINS;
    const int rf = min(max(f0, 0), BINS - 1) * BINS;
    const int cm = max(i1 - 1, 0);
    const int cc = i1;
    const int cp = min(i1 + 1, BINS - 1);
    const int cf = min(max(f1, 0), BINS - 1);

    // ---- center row: 2 packed u64 atomics over the aligned 4-col window ----
    // B1 = even window start; valid cols {i1-1, i1, i1+1} always lie inside [B1, B1+3].
    const int B1 = min(max((i1 - 1) & ~1, 0), BINS - 4);
    unsigned q[4];
    #pragma unroll
    for (int k = 0; k < 4; ++k) {
        const int col = B1 + k;
        const float c = __fmul_rn(0.01f, (float)col + 0.5f);
        const float d = fabsf(__fsub_rn(x1, c));
        const float w = fmaf(-0.5f, __fadd_rn(e00, d), 0.01f);
        const bool  v = (abs(col - i1) <= 1) && (w > 0.0f);
        q[k] = v ? (unsigned)fmaf(w, QSCALE, 0.5f) : 0u;
    }
    unsigned long long* lp = (unsigned long long*)(&lh[r0 + B1]);
    atomicAdd(lp,     (unsigned long long)q[0] | ((unsigned long long)q[1] << 32));
    atomicAdd(lp + 1, (unsigned long long)q[2] | ((unsigned long long)q[3] << 32));

    // ---- outer rows: edge uncond u32 (always fires when row valid), corners masked ----
#define SITEU(EA, EB, ADDR) do {                                               \
        const float w_ = fmaxf(fmaf(-0.5f, __fadd_rn(EA, EB), 0.01f), 0.0f);   \
        atomicAdd(&lh[ADDR], (unsigned)fmaf(w_, QSCALE, 0.5f));                \
    } while (0)
#define SITEQ(EA, EB, ADDR) do {                                               \
        const float w_ = fmaf(-0.5f, __fadd_rn(EA, EB), 0.01f);                \
        if (w_ > 0.0f)                                                         \
            atomicAdd(&lh[ADDR], (unsigned)fmaf(w_, QSCALE, 0.5f));            \
    } while (0)
    SITEQ(e0m, e1m, rm + cm); SITEU(e0m, e10, rm + cc); SITEQ(e0m, e1p, rm + cp);
    SITEQ(e0p, e1m, rp + cm); SITEU(e0p, e10, rp + cc); SITEQ(e0p, e1p, rp + cp);
    SITEQ(e0f, e10, rf + cc);   // far row, own col
    SITEQ(e00, e1f, r0 + cf);   // own row, far col
#undef SITEU
#undef SITEQ
}

// ---- main path: per-block u32 LDS hist -> partials + exact u64 batch totals ----
__global__ __launch_bounds__(THREADS) void hist_part_kernel(
    const float* __restrict__ x, unsigned* __restrict__ part,
    unsigned long long* __restrict__ totals)
{
    __shared__ __align__(16) unsigned lh[NBINS2];
    uint4* lh4 = (uint4*)lh;
    for (int i = threadIdx.x; i < NBINS2 / 4; i += THREADS)
        lh4[i] = make_uint4(0u, 0u, 0u, 0u);
    __syncthreads();

    const int b  = blockIdx.x / PPB;
    const int pb = blockIdx.x % PPB;
    const float4* __restrict__ xp = reinterpret_cast<const float4*>(
        x + (size_t)b * (NPOINTS * 2) + (size_t)pb * (CHUNK * 2));

    #pragma unroll
    for (int k = 0; k < (CHUNK / 2) / THREADS; ++k) {
        const float4 p = xp[threadIdx.x + k * THREADS];
        accum_point_q(lh, p.x, p.y);
        accum_point_q(lh, p.z, p.w);
    }
    __syncthreads();

    uint4* __restrict__ po4 = (uint4*)(part + (size_t)blockIdx.x * NBINS2);
    unsigned long long ts = 0ull;
    for (int i = threadIdx.x; i < NBINS2 / 4; i += THREADS) {
        const uint4 v = lh4[i];
        po4[i] = v;
        ts += (unsigned long long)v.x + v.y + v.z + v.w;
    }
    #pragma unroll
    for (int off = 32; off > 0; off >>= 1) ts += __shfl_down(ts, off, 64);
    if ((threadIdx.x & 63) == 0) atomicAdd(&totals[b], ts);
}

// 160 blocks x 256 thr: thread owns one uint4 (4 bins); 32 coalesced 16B loads.
__global__ __launch_bounds__(256) void reduce_norm_kernel(
    const uint4* __restrict__ part4, const unsigned long long* __restrict__ totals,
    float4* __restrict__ out4)
{
    const int b    = blockIdx.x / 10;
    const int ch   = blockIdx.x % 10;
    const int quad = ch * 256 + threadIdx.x;   // 0..2559, 2500 active
    if (quad < NQUAD) {
        const uint4* __restrict__ pp = part4 + (size_t)b * PPB * NQUAD + quad;
        unsigned long long s0 = 0, s1 = 0, s2 = 0, s3 = 0;
        #pragma unroll
        for (int p = 0; p < PPB; ++p) {
            const uint4 v = pp[(size_t)p * NQUAD];
            s0 += v.x; s1 += v.y; s2 += v.z; s3 += v.w;
        }
        const double fac = QINV / ((double)totals[b] * QINV + 1e-5);
        out4[(size_t)b * NQUAD + quad] = make_float4(
            (float)((double)s0 * fac), (float)((double)s1 * fac),
            (float)((double)s2 * fac), (float)((double)s3 * fac));
    }
}

// ---- fallback path (ws too small): float LDS hist + global atomic flush ----
__device__ __forceinline__ void accum_point_f(float* lh, float x0, float x1) {
    int i0 = __float2int_rd(__fmul_rn(x0, 100.0f)); i0 = min(max(i0, 0), BINS - 1);
    int i1 = __float2int_rd(__fmul_rn(x1, 100.0f)); i1 = min(max(i1, 0), BINS - 1);
    const float fi0 = (float)i0, fi1 = (float)i1;
    const float c00 = __fmul_rn(0.01f, fi0 + 0.5f);
    const float c10 = __fmul_rn(0.01f, fi1 + 0.5f);
    const float e00 = fabsf(__fsub_rn(x0, c00));
    const float e10 = fabsf(__fsub_rn(x1, c10));
    float e0m = fabsf(__fsub_rn(x0, __fmul_rn(0.01f, fi0 - 0.5f)));
    float e0p = fabsf(__fsub_rn(x0, __fmul_rn(0.01f, fi0 + 1.5f)));
    float e1m = fabsf(__fsub_rn(x1, __fmul_rn(0.01f, fi1 - 0.5f)));
    float e1p = fabsf(__fsub_rn(x1, __fmul_rn(0.01f, fi1 + 1.5f)));
    e0m = (i0 > 0)        ? e0m : 1e9f;
    e0p = (i0 < BINS - 1) ? e0p : 1e9f;
    e1m = (i1 > 0)        ? e1m : 1e9f;
    e1p = (i1 < BINS - 1) ? e1p : 1e9f;
    const bool up0 = (x0 > c00), up1 = (x1 > c10);
    const int   f0  = up0 ? i0 + 2 : i0 - 2;
    const int   f1  = up1 ? i1 + 2 : i1 - 2;
    const float ff0 = up0 ? fi0 + 2.0f : fi0 - 2.0f;
    const float ff1 = up1 ? fi1 + 2.0f : fi1 - 2.0f;
    float e0f = fabsf(__fsub_rn(x0, __fmul_rn(0.01f, ff0 + 0.5f)));
    float e1f = fabsf(__fsub_rn(x1, __fmul_rn(0.01f, ff1 + 0.5f)));
    e0f = ((unsigned)f0 < (unsigned)BINS) ? e0f : 1e9f;
    e1f = ((unsigned)f1 < (unsigned)BINS) ? e1f : 1e9f;
    const int rm = max(i0 - 1, 0) * BINS;
    const int r0 = i0 * BINS;
    const int rp = min(i0 + 1, BINS - 1) * BINS;
    const int rf = min(max(f0, 0), BINS - 1) * BINS;
    const int cm = max(i1 - 1, 0);
    const int cc = i1;
    const int cp = min(i1 + 1, BINS - 1);
    const int cf = min(max(f1, 0), BINS - 1);
#define SITEF(EA, EB, ADDR) do {                                               \
        const float w_ = fmaf(-0.5f, __fadd_rn(EA, EB), 0.01f);                \
        if (w_ > 0.0f) unsafeAtomicAdd(&lh[ADDR], w_);                         \
    } while (0)
    SITEF(e0m, e1m, rm + cm); SITEF(e0m, e10, rm + cc); SITEF(e0m, e1p, rm + cp);
    SITEF(e00, e1m, r0 + cm); SITEF(e00, e10, r0 + cc); SITEF(e00, e1p, r0 + cp);
    SITEF(e0p, e1m, rp + cm); SITEF(e0p, e10, rp + cc); SITEF(e0p, e1p, rp + cp);
    SITEF(e0f, e10, rf + cc);
    SITEF(e00, e1f, r0 + cf);
#undef SITEF
}

__global__ __launch_bounds__(THREADS) void hist_accum_kernel(
    const float* __restrict__ x, float* __restrict__ out)
{
    __shared__ __align__(16) float lh[NBINS2];
    float4* lh4 = (float4*)lh;
    for (int i = threadIdx.x; i < NBINS2 / 4; i += THREADS)
        lh4[i] = make_float4(0.f, 0.f, 0.f, 0.f);
    __syncthreads();
    const int b  = blockIdx.x / PPB;
    const int pb = blockIdx.x % PPB;
    const float4* __restrict__ xp = reinterpret_cast<const float4*>(
        x + (size_t)b * (NPOINTS * 2) + (size_t)pb * (CHUNK * 2));
    #pragma unroll
    for (int k = 0; k < (CHUNK / 2) / THREADS; ++k) {
        const float4 p = xp[threadIdx.x + k * THREADS];
        accum_point_f(lh, p.x, p.y);
        accum_point_f(lh, p.z, p.w);
    }
    __syncthreads();
    float* __restrict__ ob = out + (size_t)b * NBINS2;
    for (int i = threadIdx.x; i < NBINS2; i += THREADS) {
        const float v = lh[i];
        if (v != 0.0f) unsafeAtomicAdd(&ob[i], v);
    }
}

__global__ __launch_bounds__(1024) void norm_kernel(float* __restrict__ out)
{
    const int b = blockIdx.x;
    float* __restrict__ h = out + (size_t)b * NBINS2;
    float local = 0.0f;
    for (int i = threadIdx.x; i < NBINS2; i += 1024) local += h[i];
    #pragma unroll
    for (int off = 32; off > 0; off >>= 1) local += __shfl_down(local, off, 64);
    __shared__ float wsum[16];
    __shared__ float sden;
    if ((threadIdx.x & 63) == 0) wsum[threadIdx.x >> 6] = local;
    __syncthreads();
    if (threadIdx.x == 0) {
        float tt = 0.f;
        #pragma unroll
        for (int i = 0; i < 16; ++i) tt += wsum[i];
        sden = __fadd_rn(tt, 1e-5f);
    }
    __syncthreads();
    const float den = sden;
    for (int i = threadIdx.x; i < NBINS2; i += 1024) h[i] = __fdiv_rn(h[i], den);
}

extern "C" void kernel_launch(void* const* d_in, const int* in_sizes, int n_in,
                              void* d_out, int out_size, void* d_ws, size_t ws_size,
                              hipStream_t stream) {
    (void)in_sizes; (void)n_in;
    const float* x = (const float*)d_in[0];
    float* out = (float*)d_out;

    const size_t need = 128 + (size_t)NPART * NBINS2 * sizeof(unsigned);
    if (ws_size >= need) {
        unsigned long long* totals = (unsigned long long*)d_ws;        // [16]
        unsigned* part = (unsigned*)((char*)d_ws + 128);               // [512][10000]
        hipMemsetAsync(totals, 0, NBATCH * sizeof(unsigned long long), stream);
        hist_part_kernel<<<NPART, THREADS, 0, stream>>>(x, part, totals);
        reduce_norm_kernel<<<NBATCH * 10, 256, 0, stream>>>(
            (const uint4*)part, totals, (float4*)out);
    } else {
        hipMemsetAsync(out, 0, (size_t)out_size * sizeof(float), stream);
        hist_accum_kernel<<<NPART, THREADS, 0, stream>>>(x, out);
        norm_kernel<<<NBATCH, 1024, 0, stream>>>(out);
    }
}